// Round 1
// baseline (295.678 us; speedup 1.0000x reference)
//
#include <hip/hip_runtime.h>
#include <hip/hip_bf16.h>
#include <math.h>

#define N     8192
#define D     128
#define JSPLIT 8
#define BM    128
#define BN    128
#define BK    32
#define TM    8
#define TN    8
// 256 threads = 16x16 (tx over j, ty over i)

__global__ __launch_bounds__(256) void norm_kernel(const float* __restrict__ e,
                                                   float* __restrict__ rnorm) {
    int row  = blockIdx.x * 4 + (threadIdx.x >> 6);
    int lane = threadIdx.x & 63;
    float2 v = ((const float2*)(e + (size_t)row * D))[lane];
    float s = v.x * v.x + v.y * v.y;
    #pragma unroll
    for (int m = 1; m < 64; m <<= 1) s += __shfl_xor(s, m, 64);
    if (lane == 0) rnorm[row] = 1.0f / fmaxf(sqrtf(s), 1e-8f);
}

__global__ __launch_bounds__(256) void mine_kernel(
    const float* __restrict__ e, const int* __restrict__ labels,
    const float* __restrict__ rnorm,
    float* __restrict__ posv, int* __restrict__ posi,
    float* __restrict__ negv, int* __restrict__ negi) {

    __shared__ float As[BK][BM];
    __shared__ float Bs[BK][BN];

    const int tid = threadIdx.x;
    const int tx = tid & 15;
    const int ty = tid >> 4;
    const int ib = blockIdx.x;          // 0..63  (i tile)
    const int sp = blockIdx.y;          // 0..JSPLIT-1 (j split)
    const int i0 = ib * BM;
    const int jrange = N / JSPLIT;      // 1024
    const int j0base = sp * jrange;

    // per-thread anchor metadata (8 anchors: i0 + ty*8 + m)
    float rni[TM];
    int   li[TM];
    #pragma unroll
    for (int m = 0; m < TM; ++m) {
        int i = i0 + ty * TM + m;
        rni[m] = rnorm[i];
        li[m]  = labels[i];
    }

    float bpv[TM], bnv[TM];
    int   bpi[TM], bni[TM];
    #pragma unroll
    for (int m = 0; m < TM; ++m) {
        bpv[m] = -INFINITY; bpi[m] = 0;
        bnv[m] =  INFINITY; bni[m] = 0;
    }

    // staging mapping: row r = tid>>1 (0..127), k-quad = (tid&1)*16
    const int sr = tid >> 1;
    const int kq = (tid & 1) * 16;

    for (int jt = 0; jt < jrange; jt += BN) {
        const int j0 = j0base + jt;

        float acc[TM][TN];
        #pragma unroll
        for (int m = 0; m < TM; ++m)
            #pragma unroll
            for (int n = 0; n < TN; ++n) acc[m][n] = 0.0f;

        for (int kc = 0; kc < D; kc += BK) {
            __syncthreads();   // previous chunk's reads complete before overwrite
            // ---- stage A chunk (rows i0..i0+127, cols kc+kq..kc+kq+15), transposed
            {
                const float* src = e + (size_t)(i0 + sr) * D + kc + kq;
                float4 v0 = ((const float4*)src)[0];
                float4 v1 = ((const float4*)src)[1];
                float4 v2 = ((const float4*)src)[2];
                float4 v3 = ((const float4*)src)[3];
                As[kq+ 0][sr] = v0.x; As[kq+ 1][sr] = v0.y; As[kq+ 2][sr] = v0.z; As[kq+ 3][sr] = v0.w;
                As[kq+ 4][sr] = v1.x; As[kq+ 5][sr] = v1.y; As[kq+ 6][sr] = v1.z; As[kq+ 7][sr] = v1.w;
                As[kq+ 8][sr] = v2.x; As[kq+ 9][sr] = v2.y; As[kq+10][sr] = v2.z; As[kq+11][sr] = v2.w;
                As[kq+12][sr] = v3.x; As[kq+13][sr] = v3.y; As[kq+14][sr] = v3.z; As[kq+15][sr] = v3.w;
            }
            // ---- stage B chunk (rows j0..j0+127), transposed
            {
                const float* src = e + (size_t)(j0 + sr) * D + kc + kq;
                float4 v0 = ((const float4*)src)[0];
                float4 v1 = ((const float4*)src)[1];
                float4 v2 = ((const float4*)src)[2];
                float4 v3 = ((const float4*)src)[3];
                Bs[kq+ 0][sr] = v0.x; Bs[kq+ 1][sr] = v0.y; Bs[kq+ 2][sr] = v0.z; Bs[kq+ 3][sr] = v0.w;
                Bs[kq+ 4][sr] = v1.x; Bs[kq+ 5][sr] = v1.y; Bs[kq+ 6][sr] = v1.z; Bs[kq+ 7][sr] = v1.w;
                Bs[kq+ 8][sr] = v2.x; Bs[kq+ 9][sr] = v2.y; Bs[kq+10][sr] = v2.z; Bs[kq+11][sr] = v2.w;
                Bs[kq+12][sr] = v3.x; Bs[kq+13][sr] = v3.y; Bs[kq+14][sr] = v3.z; Bs[kq+15][sr] = v3.w;
            }
            __syncthreads();

            #pragma unroll 4
            for (int k = 0; k < BK; ++k) {
                float4 a0 = *(const float4*)&As[k][ty * 8];
                float4 a1 = *(const float4*)&As[k][ty * 8 + 4];
                float4 b0 = *(const float4*)&Bs[k][tx * 8];
                float4 b1 = *(const float4*)&Bs[k][tx * 8 + 4];
                float a[TM] = {a0.x, a0.y, a0.z, a0.w, a1.x, a1.y, a1.z, a1.w};
                float b[TN] = {b0.x, b0.y, b0.z, b0.w, b1.x, b1.y, b1.z, b1.w};
                #pragma unroll
                for (int m = 0; m < TM; ++m)
                    #pragma unroll
                    for (int n = 0; n < TN; ++n)
                        acc[m][n] = fmaf(a[m], b[n], acc[m][n]);
            }
        }

        // ---- epilogue for this j tile: scale, mask, update running bests
        float rnj[TN];
        int   lj[TN];
        {
            const float4* rp = (const float4*)(rnorm + j0 + tx * 8);
            float4 r0 = rp[0], r1 = rp[1];
            rnj[0]=r0.x; rnj[1]=r0.y; rnj[2]=r0.z; rnj[3]=r0.w;
            rnj[4]=r1.x; rnj[5]=r1.y; rnj[6]=r1.z; rnj[7]=r1.w;
            const int4* lp = (const int4*)(labels + j0 + tx * 8);
            int4 l0 = lp[0], l1 = lp[1];
            lj[0]=l0.x; lj[1]=l0.y; lj[2]=l0.z; lj[3]=l0.w;
            lj[4]=l1.x; lj[5]=l1.y; lj[6]=l1.z; lj[7]=l1.w;
        }
        #pragma unroll
        for (int m = 0; m < TM; ++m) {
            const int i = i0 + ty * TM + m;
            #pragma unroll
            for (int n = 0; n < TN; ++n) {
                const int j = j0 + tx * 8 + n;
                float dist = 1.0f - acc[m][n] * rni[m] * rnj[n];
                if (j != i) {
                    if (lj[n] == li[m]) {
                        if (dist > bpv[m]) { bpv[m] = dist; bpi[m] = j; }   // j ascending -> strict keeps first
                    } else {
                        if (dist < bnv[m]) { bnv[m] = dist; bni[m] = j; }
                    }
                }
            }
        }
    }

    // ---- reduce across the 16 tx lanes sharing each anchor (lanes are contiguous in-wave)
    #pragma unroll
    for (int m = 0; m < TM; ++m) {
        float pv = bpv[m]; int pi = bpi[m];
        float nv = bnv[m]; int ni = bni[m];
        #pragma unroll
        for (int off = 1; off < 16; off <<= 1) {
            float opv = __shfl_xor(pv, off, 64); int opi = __shfl_xor(pi, off, 64);
            float onv = __shfl_xor(nv, off, 64); int oni = __shfl_xor(ni, off, 64);
            if (opv > pv || (opv == pv && opi < pi)) { pv = opv; pi = opi; }
            if (onv < nv || (onv == nv && oni < ni)) { nv = onv; ni = oni; }
        }
        if (tx == 0) {
            int i = i0 + ty * TM + m;
            posv[i * JSPLIT + sp] = pv; posi[i * JSPLIT + sp] = pi;
            negv[i * JSPLIT + sp] = nv; negi[i * JSPLIT + sp] = ni;
        }
    }
}

__global__ __launch_bounds__(256) void combine_kernel(
    const float* __restrict__ posv, const int* __restrict__ posi,
    const float* __restrict__ negv, const int* __restrict__ negi,
    float* __restrict__ out) {
    int a = blockIdx.x * 256 + threadIdx.x;
    float pv = -INFINITY; int pi = 0;
    float nv =  INFINITY; int ni = 0;
    #pragma unroll
    for (int s = 0; s < JSPLIT; ++s) {          // ascending splits: strict compare keeps first j
        float v = posv[a * JSPLIT + s]; int idx = posi[a * JSPLIT + s];
        if (v > pv || (v == pv && idx < pi)) { pv = v; pi = idx; }
        float w = negv[a * JSPLIT + s]; int jdx = negi[a * JSPLIT + s];
        if (w < nv || (w == nv && jdx < ni)) { nv = w; ni = jdx; }
    }
    out[a * 3 + 0] = (float)a;
    out[a * 3 + 1] = (float)pi;
    out[a * 3 + 2] = (float)ni;
    out[3 * N + a] = pv;
    out[4 * N + a] = nv;
}

extern "C" void kernel_launch(void* const* d_in, const int* in_sizes, int n_in,
                              void* d_out, int out_size, void* d_ws, size_t ws_size,
                              hipStream_t stream) {
    const float* e      = (const float*)d_in[0];
    const int*   labels = (const int*)d_in[1];
    float* out = (float*)d_out;

    float* rn   = (float*)d_ws;
    float* posv = rn + N;
    int*   posi = (int*)(posv + N * JSPLIT);
    float* negv = (float*)(posi + N * JSPLIT);
    int*   negi = (int*)(negv + N * JSPLIT);

    norm_kernel<<<N / 4, 256, 0, stream>>>(e, rn);
    mine_kernel<<<dim3(N / BM, JSPLIT), 256, 0, stream>>>(e, labels, rn, posv, posi, negv, negi);
    combine_kernel<<<N / 256, 256, 0, stream>>>(posv, posi, negv, negi, out);
}

// Round 2
// 292.784 us; speedup vs baseline: 1.0099x; 1.0099x over previous
//
#include <hip/hip_runtime.h>
#include <hip/hip_bf16.h>
#include <math.h>

#define N 8192
#define D 128
#define MARGIN 1e-4f
#define FLAGBIT 0x80000000
#define IDXMASK 0x1FFF

typedef __attribute__((ext_vector_type(8))) short short8;
typedef __attribute__((ext_vector_type(4))) float f32x4;

// ---------------- prep: normalize, split to bf16 hi/lo, norms, zero counter ----
__global__ __launch_bounds__(256) void prep_kernel(const float* __restrict__ e,
                                                   __hip_bfloat16* __restrict__ hi,
                                                   __hip_bfloat16* __restrict__ lo,
                                                   float* __restrict__ nrm,
                                                   int* __restrict__ counter) {
    if (blockIdx.x == 0 && threadIdx.x == 0) *counter = 0;
    int row  = blockIdx.x * 4 + (threadIdx.x >> 6);
    int lane = threadIdx.x & 63;
    float2 v = ((const float2*)(e + (size_t)row * D))[lane];
    float s = v.x * v.x + v.y * v.y;
    #pragma unroll
    for (int m = 1; m < 64; m <<= 1) s += __shfl_xor(s, m, 64);
    float nr = sqrtf(s);
    if (lane == 0) nrm[row] = nr;
    float rn = 1.0f / fmaxf(nr, 1e-8f);
    float e0 = v.x * rn, e1 = v.y * rn;
    __hip_bfloat16 h0 = __float2bfloat16(e0);
    __hip_bfloat16 h1 = __float2bfloat16(e1);
    __hip_bfloat16 l0 = __float2bfloat16(e0 - __bfloat162float(h0));
    __hip_bfloat16 l1 = __float2bfloat16(e1 - __bfloat162float(h1));
    ushort2 hh, ll;
    hh.x = *(unsigned short*)&h0; hh.y = *(unsigned short*)&h1;
    ll.x = *(unsigned short*)&l0; ll.y = *(unsigned short*)&l1;
    ((ushort2*)hi)[row * 64 + lane] = hh;
    ((ushort2*)lo)[row * 64 + lane] = ll;
}

// ---------------- mine: split-bf16 MFMA GEMM + fused hardest-pos/neg ----------
__global__ __launch_bounds__(256, 2) void mine_kernel(
    const __hip_bfloat16* __restrict__ hi, const __hip_bfloat16* __restrict__ lo,
    const int* __restrict__ labels, int4* __restrict__ partials) {

    extern __shared__ short smem[];
    short* Ahi = smem;                 // 128 rows x 128 (16B-slot swizzled)
    short* Alo = Ahi + 128 * 128;
    short* Bhi = Alo + 128 * 128;      // 128 rows x 32
    short* Blo = Bhi + 128 * 32;

    const int tid = threadIdx.x;
    const int l = tid & 63;
    const int w = tid >> 6;
    const int ihalf = w >> 1, jhalf = w & 1;
    const int i0 = blockIdx.x * 128;
    const int j0base = blockIdx.y * 512;
    const int lq = l >> 4;             // 0..3
    const int ln = l & 15;

    // ---- stage A (hi+lo, full K) once, swizzled: slot' = c ^ (r&7)
    {
        const int arr = tid >> 7;      // 0 = hi, 1 = lo
        const int r = tid & 127;
        const __hip_bfloat16* src = (arr ? lo : hi) + (size_t)(i0 + r) * D;
        short* dst = (arr ? Alo : Ahi) + r * 128;
        #pragma unroll
        for (int c = 0; c < 16; ++c) {
            short8 vv = *(const short8*)(src + c * 8);
            *(short8*)(dst + ((c ^ (r & 7)) * 8)) = vv;
        }
    }
    __syncthreads();

    // per-lane anchor labels / index bases
    int li[16];
    int ibase[4];
    #pragma unroll
    for (int mt = 0; mt < 4; ++mt) ibase[mt] = i0 + ihalf * 64 + mt * 16 + lq * 4;
    #pragma unroll
    for (int s = 0; s < 16; ++s) li[s] = labels[ibase[s >> 2] + (s & 3)];

    float posv[16], negv[16];
    int   posi[16], negi[16];
    #pragma unroll
    for (int s = 0; s < 16; ++s) {
        posv[s] = -INFINITY; posi[s] = 0;
        negv[s] =  INFINITY; negi[s] = 0;
    }

    for (int jt = 0; jt < 4; ++jt) {
        const int j0 = j0base + jt * 128;

        f32x4 acc[4][4];
        #pragma unroll
        for (int mt = 0; mt < 4; ++mt)
            #pragma unroll
            for (int nt = 0; nt < 4; ++nt) acc[mt][nt] = (f32x4){0.f, 0.f, 0.f, 0.f};

        for (int kc = 0; kc < 4; ++kc) {
            __syncthreads();
            // stage B chunk (hi+lo, 128 rows x 32 dims) via global_load_lds w=16
            #pragma unroll
            for (int p = 0; p < 4; ++p) {
                int f = w * 4 + p;
                int arr = f >> 3, rg = f & 7;
                int r = rg * 16 + (l >> 2);
                int gg = (l & 3) ^ ((r >> 1) & 3);     // source-side swizzle
                const __hip_bfloat16* gsrc =
                    (arr ? lo : hi) + (size_t)(j0 + r) * D + kc * 32 + gg * 8;
                short* lbase = (arr ? Blo : Bhi) + rg * 512;
                __builtin_amdgcn_global_load_lds(
                    (const __attribute__((address_space(1))) void*)gsrc,
                    (__attribute__((address_space(3))) void*)lbase, 16, 0, 0);
            }
            __syncthreads();

            // B fragments cached in registers
            short8 bh4[4], bl4[4];
            #pragma unroll
            for (int nt = 0; nt < 4; ++nt) {
                int r = jhalf * 64 + nt * 16 + ln;
                int gslot = lq ^ ((r >> 1) & 3);
                bh4[nt] = *(short8*)(Bhi + r * 32 + gslot * 8);
                bl4[nt] = *(short8*)(Blo + r * 32 + gslot * 8);
            }
            #pragma unroll
            for (int mt = 0; mt < 4; ++mt) {
                int r = ihalf * 64 + mt * 16 + ln;
                int slot = (kc * 4 + lq) ^ (r & 7);
                short8 ah = *(short8*)(Ahi + r * 128 + slot * 8);
                short8 al = *(short8*)(Alo + r * 128 + slot * 8);
                #pragma unroll
                for (int nt = 0; nt < 4; ++nt) {
                    acc[mt][nt] = __builtin_amdgcn_mfma_f32_16x16x32_bf16(ah, bh4[nt], acc[mt][nt], 0, 0, 0);
                    acc[mt][nt] = __builtin_amdgcn_mfma_f32_16x16x32_bf16(ah, bl4[nt], acc[mt][nt], 0, 0, 0);
                    acc[mt][nt] = __builtin_amdgcn_mfma_f32_16x16x32_bf16(al, bh4[nt], acc[mt][nt], 0, 0, 0);
                }
            }
        }

        // ---- epilogue: update running hardest pos/neg (+near-tie flags)
        int jv[4], lj[4];
        #pragma unroll
        for (int nt = 0; nt < 4; ++nt) {
            jv[nt] = j0 + jhalf * 64 + nt * 16 + ln;
            lj[nt] = labels[jv[nt]];
        }
        #pragma unroll
        for (int nt = 0; nt < 4; ++nt) {
            #pragma unroll
            for (int mt = 0; mt < 4; ++mt) {
                #pragma unroll
                for (int r = 0; r < 4; ++r) {
                    const int s = mt * 4 + r;
                    float dd = 1.0f - acc[mt][nt][r];
                    bool same = (lj[nt] == li[s]);
                    bool self = (jv[nt] == ibase[mt] + r);
                    if (same) {
                        if (!self) {
                            bool nr = fabsf(dd - posv[s]) < MARGIN;
                            if (dd > posv[s]) { posv[s] = dd; posi[s] = jv[nt] | (nr ? FLAGBIT : 0); }
                            else if (nr) posi[s] |= FLAGBIT;
                        }
                    } else {
                        bool nr = fabsf(dd - negv[s]) < MARGIN;
                        if (dd < negv[s]) { negv[s] = dd; negi[s] = jv[nt] | (nr ? FLAGBIT : 0); }
                        else if (nr) negi[s] |= FLAGBIT;
                    }
                }
            }
        }
    }

    // ---- cross-lane (16 lanes share each anchor set) butterfly + partial write
    #pragma unroll
    for (int s = 0; s < 16; ++s) {
        float pv = posv[s]; int pif = posi[s];
        float nv = negv[s]; int nif = negi[s];
        #pragma unroll
        for (int off = 1; off < 16; off <<= 1) {
            float opv = __shfl_xor(pv, off, 64); int opif = __shfl_xor(pif, off, 64);
            float onv = __shfl_xor(nv, off, 64); int onif = __shfl_xor(nif, off, 64);
            bool pnr = fabsf(opv - pv) < MARGIN;
            bool nnr = fabsf(onv - nv) < MARGIN;
            if (opv > pv) { pv = opv; pif = opif; }
            if (pnr) pif |= FLAGBIT;
            if (onv < nv) { nv = onv; nif = onif; }
            if (nnr) nif |= FLAGBIT;
        }
        if (ln == s) {
            int ii = ibase[s >> 2] + (s & 3);
            partials[ii * 32 + blockIdx.y * 2 + jhalf] =
                make_int4(__float_as_int(pv), pif, __float_as_int(nv), nif);
        }
    }
}

// ---------------- combine: fold 32 partials/row, write outputs, flag rows ----
__global__ __launch_bounds__(256) void combine_kernel(
    const int4* __restrict__ partials, float* __restrict__ out,
    int* __restrict__ list, int* __restrict__ counter) {
    int a = blockIdx.x * 256 + threadIdx.x;
    float pv = -INFINITY; int pif = 0;
    float nv =  INFINITY; int nif = 0;
    #pragma unroll
    for (int sl = 0; sl < 32; ++sl) {
        int4 p = partials[a * 32 + sl];
        float dv = __int_as_float(p.x);
        bool nr = fabsf(dv - pv) < MARGIN;
        if (dv > pv) { pv = dv; pif = p.y; }
        if (nr) pif |= FLAGBIT;
        float ev = __int_as_float(p.z);
        bool nr2 = fabsf(ev - nv) < MARGIN;
        if (ev < nv) { nv = ev; nif = p.w; }
        if (nr2) nif |= FLAGBIT;
    }
    out[a * 3 + 0] = (float)a;
    out[a * 3 + 1] = (float)(pif & IDXMASK);
    out[a * 3 + 2] = (float)(nif & IDXMASK);
    out[3 * N + a] = pv;
    out[4 * N + a] = nv;
    if ((pif | nif) & FLAGBIT) {
        int k = atomicAdd(counter, 1);
        list[k] = a;
    }
}

// ---------------- cleanup: exact fp32 recompute for flagged rows -------------
__global__ __launch_bounds__(256) void cleanup_kernel(
    const float* __restrict__ e, const int* __restrict__ labels,
    const float* __restrict__ nrm, const int* __restrict__ list,
    const int* __restrict__ counter, float* __restrict__ out) {
    __shared__ float enr[128];
    __shared__ float sp[4]; __shared__ int spi[4];
    __shared__ float sn[4]; __shared__ int sni[4];
    const int tid = threadIdx.x;
    const int lane = tid & 63, w = tid >> 6;
    const int cnt = *counter;
    for (int it = blockIdx.x; it < cnt; it += gridDim.x) {
        __syncthreads();
        int rrow = list[it];
        if (tid < 128) enr[tid] = e[(size_t)rrow * D + tid] / fmaxf(nrm[rrow], 1e-8f);
        __syncthreads();
        int lr = labels[rrow];
        float pv = -INFINITY; int pi = 0;
        float nv =  INFINITY; int ni = 0;
        for (int j = tid; j < N; j += 256) {
            if (j == rrow) continue;
            const float4* ej = (const float4*)(e + (size_t)j * D);
            float s = 0.f;
            #pragma unroll
            for (int c = 0; c < 32; ++c) {
                float4 v = ej[c];
                s = fmaf(v.x, enr[c * 4 + 0],
                    fmaf(v.y, enr[c * 4 + 1],
                    fmaf(v.z, enr[c * 4 + 2],
                    fmaf(v.w, enr[c * 4 + 3], s))));
            }
            float dd = 1.0f - s / fmaxf(nrm[j], 1e-8f);
            if (labels[j] == lr) {
                if (dd > pv || (dd == pv && j < pi)) { pv = dd; pi = j; }
            } else {
                if (dd < nv || (dd == nv && j < ni)) { nv = dd; ni = j; }
            }
        }
        #pragma unroll
        for (int off = 1; off < 64; off <<= 1) {
            float o = __shfl_xor(pv, off, 64); int oi = __shfl_xor(pi, off, 64);
            if (o > pv || (o == pv && oi < pi)) { pv = o; pi = oi; }
            float o2 = __shfl_xor(nv, off, 64); int oi2 = __shfl_xor(ni, off, 64);
            if (o2 < nv || (o2 == nv && oi2 < ni)) { nv = o2; ni = oi2; }
        }
        if (lane == 0) { sp[w] = pv; spi[w] = pi; sn[w] = nv; sni[w] = ni; }
        __syncthreads();
        if (tid == 0) {
            float fpv = sp[0]; int fpi = spi[0];
            float fnv = sn[0]; int fni = sni[0];
            #pragma unroll
            for (int q = 1; q < 4; ++q) {
                if (sp[q] > fpv || (sp[q] == fpv && spi[q] < fpi)) { fpv = sp[q]; fpi = spi[q]; }
                if (sn[q] < fnv || (sn[q] == fnv && sni[q] < fni)) { fnv = sn[q]; fni = sni[q]; }
            }
            out[rrow * 3 + 1] = (float)fpi;
            out[rrow * 3 + 2] = (float)fni;
            out[3 * N + rrow] = fpv;
            out[4 * N + rrow] = fnv;
        }
    }
}

extern "C" void kernel_launch(void* const* d_in, const int* in_sizes, int n_in,
                              void* d_out, int out_size, void* d_ws, size_t ws_size,
                              hipStream_t stream) {
    const float* e      = (const float*)d_in[0];
    const int*   labels = (const int*)d_in[1];
    float* out = (float*)d_out;

    char* wsb = (char*)d_ws;
    __hip_bfloat16* hi = (__hip_bfloat16*)wsb;                          // 2 MB
    __hip_bfloat16* lo = hi + (size_t)N * D;                            // 2 MB
    float* nrm   = (float*)(wsb + 4u * 1024 * 1024);                    // 32 KB
    int4*  parts = (int4*)(wsb + 4u * 1024 * 1024 + 65536);             // 4 MB
    int*   list  = (int*)(wsb + 8u * 1024 * 1024 + 65536);              // 32 KB
    int*   cnt   = (int*)(wsb + 8u * 1024 * 1024 + 131072);             // 4 B

    prep_kernel<<<N / 4, 256, 0, stream>>>(e, hi, lo, nrm, cnt);
    mine_kernel<<<dim3(N / 128, 16), 256, 81920, stream>>>(hi, lo, labels, parts);
    combine_kernel<<<N / 256, 256, 0, stream>>>(parts, out, list, cnt);
    cleanup_kernel<<<64, 256, 0, stream>>>(e, labels, nrm, list, cnt, out);
}

// Round 3
// 291.860 us; speedup vs baseline: 1.0131x; 1.0032x over previous
//
#include <hip/hip_runtime.h>
#include <hip/hip_bf16.h>
#include <math.h>

#define N 8192
#define D 128
#define MARGIN 4e-5f
#define FLAGBIT 0x80000000
#define IDXMASK 0x1FFF

typedef __attribute__((ext_vector_type(8))) short short8;
typedef __attribute__((ext_vector_type(4))) float f32x4;

// ---------------- prep: normalize, split to bf16 hi/lo, norms, zero counter ----
__global__ __launch_bounds__(256) void prep_kernel(const float* __restrict__ e,
                                                   __hip_bfloat16* __restrict__ hi,
                                                   __hip_bfloat16* __restrict__ lo,
                                                   float* __restrict__ nrm,
                                                   int* __restrict__ counter) {
    if (blockIdx.x == 0 && threadIdx.x == 0) *counter = 0;
    int row  = blockIdx.x * 4 + (threadIdx.x >> 6);
    int lane = threadIdx.x & 63;
    float2 v = ((const float2*)(e + (size_t)row * D))[lane];
    float s = v.x * v.x + v.y * v.y;
    #pragma unroll
    for (int m = 1; m < 64; m <<= 1) s += __shfl_xor(s, m, 64);
    float nr = sqrtf(s);
    if (lane == 0) nrm[row] = nr;
    float rn = 1.0f / fmaxf(nr, 1e-8f);
    float e0 = v.x * rn, e1 = v.y * rn;
    __hip_bfloat16 h0 = __float2bfloat16(e0);
    __hip_bfloat16 h1 = __float2bfloat16(e1);
    __hip_bfloat16 l0 = __float2bfloat16(e0 - __bfloat162float(h0));
    __hip_bfloat16 l1 = __float2bfloat16(e1 - __bfloat162float(h1));
    ushort2 hh, ll;
    hh.x = *(unsigned short*)&h0; hh.y = *(unsigned short*)&h1;
    ll.x = *(unsigned short*)&l0; ll.y = *(unsigned short*)&l1;
    ((ushort2*)hi)[row * 64 + lane] = hh;
    ((ushort2*)lo)[row * 64 + lane] = ll;
}

// ---------------- mine: A LDS-resident, B frags direct from L2, no main-loop barriers
__global__ __launch_bounds__(256, 2) void mine_kernel(
    const __hip_bfloat16* __restrict__ hi, const __hip_bfloat16* __restrict__ lo,
    const int* __restrict__ labels, int4* __restrict__ partials) {

    __shared__ short Ahi[128 * 128];
    __shared__ short Alo[128 * 128];
    __shared__ int   lab_sh[1024];

    const int tid = threadIdx.x;
    const int l = tid & 63;
    const int w = tid >> 6;
    const int ihalf = w >> 1, jhalf = w & 1;
    const int i0 = blockIdx.x * 128;
    const int j0base = blockIdx.y * 1024;
    const int lq = l >> 4;             // 0..3  (k-chunk of 8 dims)
    const int ln = l & 15;             // row/col within 16-tile

    // ---- stage A (hi+lo, full K=128) once, swizzled: chunk c stored at slot c^(r&7)
    {
        const int arr = tid >> 7;      // 0 = hi, 1 = lo
        const int r = tid & 127;
        const __hip_bfloat16* src = (arr ? lo : hi) + (size_t)(i0 + r) * D;
        short* dst = (arr ? Alo : Ahi) + r * 128;
        #pragma unroll
        for (int c = 0; c < 16; ++c) {
            short8 vv = *(const short8*)(src + c * 8);
            *(short8*)(dst + ((c ^ (r & 7)) * 8)) = vv;
        }
    }
    // ---- stage labels for this block's j-range
    {
        int4 lv = ((const int4*)(labels + j0base))[tid];
        ((int4*)lab_sh)[tid] = lv;
    }
    __syncthreads();   // the only barrier

    // per-lane anchor labels / index bases
    int li[16];
    int ibase[4];
    #pragma unroll
    for (int mt = 0; mt < 4; ++mt) ibase[mt] = i0 + ihalf * 64 + mt * 16 + lq * 4;
    #pragma unroll
    for (int s = 0; s < 16; ++s) li[s] = labels[ibase[s >> 2] + (s & 3)];

    float posv[16], negv[16];
    int   posi[16], negi[16];
    #pragma unroll
    for (int s = 0; s < 16; ++s) {
        posv[s] = -INFINITY; posi[s] = 0;
        negv[s] =  INFINITY; negi[s] = 0;
    }

    const short* hs = (const short*)hi;
    const short* ls = (const short*)lo;

    for (int jt = 0; jt < 8; ++jt) {
        const int j0 = j0base + jt * 128;
        const int jrow0 = j0 + jhalf * 64 + ln;   // + nt*16

        f32x4 acc[4][4];
        #pragma unroll
        for (int mt = 0; mt < 4; ++mt)
            #pragma unroll
            for (int nt = 0; nt < 4; ++nt) acc[mt][nt] = (f32x4){0.f, 0.f, 0.f, 0.f};

        #pragma unroll 2
        for (int kc = 0; kc < 4; ++kc) {
            // ---- B fragments straight from global (L2-resident)
            short8 bh4[4], bl4[4];
            #pragma unroll
            for (int nt = 0; nt < 4; ++nt) {
                size_t off = (size_t)(jrow0 + nt * 16) * D + kc * 32 + lq * 8;
                bh4[nt] = *(const short8*)(hs + off);
                bl4[nt] = *(const short8*)(ls + off);
            }
            // ---- A fragments from LDS (swizzled, conflict-free in 8-lane phases)
            #pragma unroll
            for (int mt = 0; mt < 4; ++mt) {
                int r = ihalf * 64 + mt * 16 + ln;
                int slot = (kc * 4 + lq) ^ (ln & 7);
                short8 ah = *(short8*)(Ahi + r * 128 + slot * 8);
                short8 al = *(short8*)(Alo + r * 128 + slot * 8);
                #pragma unroll
                for (int nt = 0; nt < 4; ++nt) {
                    acc[mt][nt] = __builtin_amdgcn_mfma_f32_16x16x32_bf16(ah, bh4[nt], acc[mt][nt], 0, 0, 0);
                    acc[mt][nt] = __builtin_amdgcn_mfma_f32_16x16x32_bf16(ah, bl4[nt], acc[mt][nt], 0, 0, 0);
                    acc[mt][nt] = __builtin_amdgcn_mfma_f32_16x16x32_bf16(al, bh4[nt], acc[mt][nt], 0, 0, 0);
                }
            }
        }

        // ---- epilogue: update running hardest pos/neg (+near-tie flags)
        int jv[4], lj[4];
        #pragma unroll
        for (int nt = 0; nt < 4; ++nt) {
            jv[nt] = jrow0 + nt * 16;
            lj[nt] = lab_sh[jv[nt] - j0base];
        }
        #pragma unroll
        for (int nt = 0; nt < 4; ++nt) {
            #pragma unroll
            for (int mt = 0; mt < 4; ++mt) {
                #pragma unroll
                for (int r = 0; r < 4; ++r) {
                    const int s = mt * 4 + r;
                    float dd = 1.0f - acc[mt][nt][r];
                    bool same = (lj[nt] == li[s]);
                    bool self = (jv[nt] == ibase[mt] + r);
                    if (same) {
                        if (!self) {
                            bool nr = fabsf(dd - posv[s]) < MARGIN;
                            if (dd > posv[s]) { posv[s] = dd; posi[s] = jv[nt] | (nr ? FLAGBIT : 0); }
                            else if (nr) posi[s] |= FLAGBIT;
                        }
                    } else {
                        bool nr = fabsf(dd - negv[s]) < MARGIN;
                        if (dd < negv[s]) { negv[s] = dd; negi[s] = jv[nt] | (nr ? FLAGBIT : 0); }
                        else if (nr) negi[s] |= FLAGBIT;
                    }
                }
            }
        }
    }

    // ---- cross-lane (16 lanes share each anchor set) butterfly + partial write
    #pragma unroll
    for (int s = 0; s < 16; ++s) {
        float pv = posv[s]; int pif = posi[s];
        float nv = negv[s]; int nif = negi[s];
        #pragma unroll
        for (int off = 1; off < 16; off <<= 1) {
            float opv = __shfl_xor(pv, off, 64); int opif = __shfl_xor(pif, off, 64);
            float onv = __shfl_xor(nv, off, 64); int onif = __shfl_xor(nif, off, 64);
            bool pnr = fabsf(opv - pv) < MARGIN;
            bool nnr = fabsf(onv - nv) < MARGIN;
            if (opv > pv) { pv = opv; pif = opif; }
            if (pnr) pif |= FLAGBIT;
            if (onv < nv) { nv = onv; nif = onif; }
            if (nnr) nif |= FLAGBIT;
        }
        if (ln == s) {
            int ii = ibase[s >> 2] + (s & 3);
            partials[ii * 16 + blockIdx.y * 2 + jhalf] =
                make_int4(__float_as_int(pv), pif, __float_as_int(nv), nif);
        }
    }
}

// ---------------- combine: fold 16 partials/row (4 lanes/row), outputs + flag list
__global__ __launch_bounds__(256) void combine_kernel(
    const int4* __restrict__ partials, float* __restrict__ out,
    int* __restrict__ list, int* __restrict__ counter) {
    int tid = threadIdx.x;
    int a = blockIdx.x * 64 + (tid >> 2);
    int q = tid & 3;
    float pv = -INFINITY; int pif = 0;
    float nv =  INFINITY; int nif = 0;
    #pragma unroll
    for (int s = 0; s < 4; ++s) {                  // slots q*4+s, ascending j within lane
        int4 p = partials[a * 16 + q * 4 + s];
        float dv = __int_as_float(p.x);
        bool nr = fabsf(dv - pv) < MARGIN;
        if (dv > pv) { pv = dv; pif = p.y; }
        if (nr) pif |= FLAGBIT;
        float ev = __int_as_float(p.z);
        bool nr2 = fabsf(ev - nv) < MARGIN;
        if (ev < nv) { nv = ev; nif = p.w; }
        if (nr2) nif |= FLAGBIT;
    }
    #pragma unroll
    for (int off = 1; off < 4; off <<= 1) {        // merge the 4 lanes of this row
        float opv = __shfl_xor(pv, off, 64); int opif = __shfl_xor(pif, off, 64);
        float onv = __shfl_xor(nv, off, 64); int onif = __shfl_xor(nif, off, 64);
        bool pnr = fabsf(opv - pv) < MARGIN;
        bool nnr = fabsf(onv - nv) < MARGIN;
        int opidx = opif & IDXMASK, pidx = pif & IDXMASK;
        if (opv > pv || (opv == pv && opidx < pidx)) { pv = opv; pif = opif; }
        if (pnr) pif |= FLAGBIT;
        int onidx = onif & IDXMASK, nidx = nif & IDXMASK;
        if (onv < nv || (onv == nv && onidx < nidx)) { nv = onv; nif = onif; }
        if (nnr) nif |= FLAGBIT;
    }
    if (q == 0) {
        out[a * 3 + 0] = (float)a;
        out[a * 3 + 1] = (float)(pif & IDXMASK);
        out[a * 3 + 2] = (float)(nif & IDXMASK);
        out[3 * N + a] = pv;
        out[4 * N + a] = nv;
        if ((pif | nif) & FLAGBIT) {
            int k = atomicAdd(counter, 1);
            list[k] = a;
        }
    }
}

// ---------------- cleanup: exact fp32 recompute for flagged rows -------------
__global__ __launch_bounds__(256) void cleanup_kernel(
    const float* __restrict__ e, const int* __restrict__ labels,
    const float* __restrict__ nrm, const int* __restrict__ list,
    const int* __restrict__ counter, float* __restrict__ out) {
    __shared__ float enr[128];
    __shared__ float sp[4]; __shared__ int spi[4];
    __shared__ float sn[4]; __shared__ int sni[4];
    const int tid = threadIdx.x;
    const int lane = tid & 63, w = tid >> 6;
    const int cnt = *counter;
    for (int it = blockIdx.x; it < cnt; it += gridDim.x) {
        __syncthreads();
        int rrow = list[it];
        if (tid < 128) enr[tid] = e[(size_t)rrow * D + tid] / fmaxf(nrm[rrow], 1e-8f);
        __syncthreads();
        int lr = labels[rrow];
        float pv = -INFINITY; int pi = 0;
        float nv =  INFINITY; int ni = 0;
        for (int j = tid; j < N; j += 256) {
            if (j == rrow) continue;
            const float4* ej = (const float4*)(e + (size_t)j * D);
            float s = 0.f;
            #pragma unroll
            for (int c = 0; c < 32; ++c) {
                float4 v = ej[c];
                s = fmaf(v.x, enr[c * 4 + 0],
                    fmaf(v.y, enr[c * 4 + 1],
                    fmaf(v.z, enr[c * 4 + 2],
                    fmaf(v.w, enr[c * 4 + 3], s))));
            }
            float dd = 1.0f - s / fmaxf(nrm[j], 1e-8f);
            if (labels[j] == lr) {
                if (dd > pv || (dd == pv && j < pi)) { pv = dd; pi = j; }
            } else {
                if (dd < nv || (dd == nv && j < ni)) { nv = dd; ni = j; }
            }
        }
        #pragma unroll
        for (int off = 1; off < 64; off <<= 1) {
            float o = __shfl_xor(pv, off, 64); int oi = __shfl_xor(pi, off, 64);
            if (o > pv || (o == pv && oi < pi)) { pv = o; pi = oi; }
            float o2 = __shfl_xor(nv, off, 64); int oi2 = __shfl_xor(ni, off, 64);
            if (o2 < nv || (o2 == nv && oi2 < ni)) { nv = o2; ni = oi2; }
        }
        if (lane == 0) { sp[w] = pv; spi[w] = pi; sn[w] = nv; sni[w] = ni; }
        __syncthreads();
        if (tid == 0) {
            float fpv = sp[0]; int fpi = spi[0];
            float fnv = sn[0]; int fni = sni[0];
            #pragma unroll
            for (int q = 1; q < 4; ++q) {
                if (sp[q] > fpv || (sp[q] == fpv && spi[q] < fpi)) { fpv = sp[q]; fpi = spi[q]; }
                if (sn[q] < fnv || (sn[q] == fnv && sni[q] < fni)) { fnv = sn[q]; fni = sni[q]; }
            }
            out[rrow * 3 + 1] = (float)fpi;
            out[rrow * 3 + 2] = (float)fni;
            out[3 * N + rrow] = fpv;
            out[4 * N + rrow] = fnv;
        }
    }
}

extern "C" void kernel_launch(void* const* d_in, const int* in_sizes, int n_in,
                              void* d_out, int out_size, void* d_ws, size_t ws_size,
                              hipStream_t stream) {
    const float* e      = (const float*)d_in[0];
    const int*   labels = (const int*)d_in[1];
    float* out = (float*)d_out;

    char* wsb = (char*)d_ws;
    __hip_bfloat16* hi = (__hip_bfloat16*)wsb;                          // 2 MB
    __hip_bfloat16* lo = hi + (size_t)N * D;                            // 2 MB
    float* nrm   = (float*)(wsb + 4u * 1024 * 1024);                    // 32 KB
    int4*  parts = (int4*)(wsb + 4u * 1024 * 1024 + 65536);             // 2 MB
    int*   list  = (int*)(wsb + 7u * 1024 * 1024);                      // 32 KB
    int*   cnt   = (int*)(wsb + 7u * 1024 * 1024 + 65536);              // 4 B

    prep_kernel<<<N / 4, 256, 0, stream>>>(e, hi, lo, nrm, cnt);
    mine_kernel<<<dim3(N / 128, 8), 256, 0, stream>>>(hi, lo, labels, parts);
    combine_kernel<<<N / 64, 256, 0, stream>>>(parts, out, list, cnt);
    cleanup_kernel<<<256, 256, 0, stream>>>(e, labels, nrm, list, cnt, out);
}

// Round 4
// 178.003 us; speedup vs baseline: 1.6611x; 1.6396x over previous
//
#include <hip/hip_runtime.h>
#include <hip/hip_bf16.h>
#include <math.h>

#define N 8192
#define D 128
#define MARGIN 4e-5f
#define FLAGBIT 0x80000000
#define IDXMASK 0x1FFF

typedef __attribute__((ext_vector_type(8))) short short8;
typedef __attribute__((ext_vector_type(4))) float f32x4;
typedef unsigned long long u64;

__device__ __forceinline__ unsigned int ordered_u32(float f) {
    unsigned int b = __float_as_uint(f);
    return (b & 0x80000000u) ? ~b : (b | 0x80000000u);
}
__device__ __forceinline__ float ordered_inv(unsigned int u) {
    unsigned int b = (u & 0x80000000u) ? (u & 0x7FFFFFFFu) : ~u;
    return __uint_as_float(b);
}

// ---------------- prep: normalize, split to bf16 hi/lo, norms, init keys/counter
__global__ __launch_bounds__(256) void prep_kernel(const float* __restrict__ e,
                                                   __hip_bfloat16* __restrict__ hi,
                                                   __hip_bfloat16* __restrict__ lo,
                                                   float* __restrict__ nrm,
                                                   int* __restrict__ counter,
                                                   u64* __restrict__ pos_key,
                                                   u64* __restrict__ neg_key) {
    if (blockIdx.x == 0 && threadIdx.x == 0) *counter = 0;
    int row  = blockIdx.x * 4 + (threadIdx.x >> 6);
    int lane = threadIdx.x & 63;
    if (lane == 0) { pos_key[row] = ~0ull; neg_key[row] = ~0ull; }
    float2 v = ((const float2*)(e + (size_t)row * D))[lane];
    float s = v.x * v.x + v.y * v.y;
    #pragma unroll
    for (int m = 1; m < 64; m <<= 1) s += __shfl_xor(s, m, 64);
    float nr = sqrtf(s);
    if (lane == 0) nrm[row] = nr;
    float rn = 1.0f / fmaxf(nr, 1e-8f);
    float e0 = v.x * rn, e1 = v.y * rn;
    __hip_bfloat16 h0 = __float2bfloat16(e0);
    __hip_bfloat16 h1 = __float2bfloat16(e1);
    __hip_bfloat16 l0 = __float2bfloat16(e0 - __bfloat162float(h0));
    __hip_bfloat16 l1 = __float2bfloat16(e1 - __bfloat162float(h1));
    ushort2 hh, ll;
    hh.x = *(unsigned short*)&h0; hh.y = *(unsigned short*)&h1;
    ll.x = *(unsigned short*)&l0; ll.y = *(unsigned short*)&l1;
    ((ushort2*)hi)[row * 64 + lane] = hh;
    ((ushort2*)lo)[row * 64 + lane] = ll;
}

// ---------------- mine: A LDS-resident, B frags direct from L2, no main-loop barriers
__global__ __launch_bounds__(256, 2) void mine_kernel(
    const __hip_bfloat16* __restrict__ hi, const __hip_bfloat16* __restrict__ lo,
    const int* __restrict__ labels, int4* __restrict__ partials) {

    __shared__ short Ahi[128 * 128];
    __shared__ short Alo[128 * 128];
    __shared__ int   lab_sh[1024];

    const int tid = threadIdx.x;
    const int l = tid & 63;
    const int w = tid >> 6;
    const int ihalf = w >> 1, jhalf = w & 1;
    const int i0 = blockIdx.x * 128;
    const int j0base = blockIdx.y * 1024;
    const int lq = l >> 4;
    const int ln = l & 15;

    {
        const int arr = tid >> 7;
        const int r = tid & 127;
        const __hip_bfloat16* src = (arr ? lo : hi) + (size_t)(i0 + r) * D;
        short* dst = (arr ? Alo : Ahi) + r * 128;
        #pragma unroll
        for (int c = 0; c < 16; ++c) {
            short8 vv = *(const short8*)(src + c * 8);
            *(short8*)(dst + ((c ^ (r & 7)) * 8)) = vv;
        }
    }
    {
        int4 lv = ((const int4*)(labels + j0base))[tid];
        ((int4*)lab_sh)[tid] = lv;
    }
    __syncthreads();

    int li[16];
    int ibase[4];
    #pragma unroll
    for (int mt = 0; mt < 4; ++mt) ibase[mt] = i0 + ihalf * 64 + mt * 16 + lq * 4;
    #pragma unroll
    for (int s = 0; s < 16; ++s) li[s] = labels[ibase[s >> 2] + (s & 3)];

    float posv[16], negv[16];
    int   posi[16], negi[16];
    #pragma unroll
    for (int s = 0; s < 16; ++s) {
        posv[s] = -INFINITY; posi[s] = 0;
        negv[s] =  INFINITY; negi[s] = 0;
    }

    const short* hs = (const short*)hi;
    const short* ls = (const short*)lo;

    for (int jt = 0; jt < 8; ++jt) {
        const int j0 = j0base + jt * 128;
        const int jrow0 = j0 + jhalf * 64 + ln;

        f32x4 acc[4][4];
        #pragma unroll
        for (int mt = 0; mt < 4; ++mt)
            #pragma unroll
            for (int nt = 0; nt < 4; ++nt) acc[mt][nt] = (f32x4){0.f, 0.f, 0.f, 0.f};

        #pragma unroll 2
        for (int kc = 0; kc < 4; ++kc) {
            short8 bh4[4], bl4[4];
            #pragma unroll
            for (int nt = 0; nt < 4; ++nt) {
                size_t off = (size_t)(jrow0 + nt * 16) * D + kc * 32 + lq * 8;
                bh4[nt] = *(const short8*)(hs + off);
                bl4[nt] = *(const short8*)(ls + off);
            }
            #pragma unroll
            for (int mt = 0; mt < 4; ++mt) {
                int r = ihalf * 64 + mt * 16 + ln;
                int slot = (kc * 4 + lq) ^ (ln & 7);
                short8 ah = *(short8*)(Ahi + r * 128 + slot * 8);
                short8 al = *(short8*)(Alo + r * 128 + slot * 8);
                #pragma unroll
                for (int nt = 0; nt < 4; ++nt) {
                    acc[mt][nt] = __builtin_amdgcn_mfma_f32_16x16x32_bf16(ah, bh4[nt], acc[mt][nt], 0, 0, 0);
                    acc[mt][nt] = __builtin_amdgcn_mfma_f32_16x16x32_bf16(ah, bl4[nt], acc[mt][nt], 0, 0, 0);
                    acc[mt][nt] = __builtin_amdgcn_mfma_f32_16x16x32_bf16(al, bh4[nt], acc[mt][nt], 0, 0, 0);
                }
            }
        }

        int jv[4], lj[4];
        #pragma unroll
        for (int nt = 0; nt < 4; ++nt) {
            jv[nt] = jrow0 + nt * 16;
            lj[nt] = lab_sh[jv[nt] - j0base];
        }
        #pragma unroll
        for (int nt = 0; nt < 4; ++nt) {
            #pragma unroll
            for (int mt = 0; mt < 4; ++mt) {
                #pragma unroll
                for (int r = 0; r < 4; ++r) {
                    const int s = mt * 4 + r;
                    float dd = 1.0f - acc[mt][nt][r];
                    bool same = (lj[nt] == li[s]);
                    bool self = (jv[nt] == ibase[mt] + r);
                    if (same) {
                        if (!self) {
                            bool nr = fabsf(dd - posv[s]) < MARGIN;
                            if (dd > posv[s]) { posv[s] = dd; posi[s] = jv[nt] | (nr ? FLAGBIT : 0); }
                            else if (nr) posi[s] |= FLAGBIT;
                        }
                    } else {
                        bool nr = fabsf(dd - negv[s]) < MARGIN;
                        if (dd < negv[s]) { negv[s] = dd; negi[s] = jv[nt] | (nr ? FLAGBIT : 0); }
                        else if (nr) negi[s] |= FLAGBIT;
                    }
                }
            }
        }
    }

    #pragma unroll
    for (int s = 0; s < 16; ++s) {
        float pv = posv[s]; int pif = posi[s];
        float nv = negv[s]; int nif = negi[s];
        #pragma unroll
        for (int off = 1; off < 16; off <<= 1) {
            float opv = __shfl_xor(pv, off, 64); int opif = __shfl_xor(pif, off, 64);
            float onv = __shfl_xor(nv, off, 64); int onif = __shfl_xor(nif, off, 64);
            bool pnr = fabsf(opv - pv) < MARGIN;
            bool nnr = fabsf(onv - nv) < MARGIN;
            if (opv > pv) { pv = opv; pif = opif; }
            if (pnr) pif |= FLAGBIT;
            if (onv < nv) { nv = onv; nif = onif; }
            if (nnr) nif |= FLAGBIT;
        }
        if (ln == s) {
            int ii = ibase[s >> 2] + (s & 3);
            partials[ii * 16 + blockIdx.y * 2 + jhalf] =
                make_int4(__float_as_int(pv), pif, __float_as_int(nv), nif);
        }
    }
}

// ---------------- combine: fold 16 partials/row (4 lanes/row), outputs + flag list
__global__ __launch_bounds__(256) void combine_kernel(
    const int4* __restrict__ partials, float* __restrict__ out,
    int* __restrict__ list, int* __restrict__ counter) {
    int tid = threadIdx.x;
    int a = blockIdx.x * 64 + (tid >> 2);
    int q = tid & 3;
    float pv = -INFINITY; int pif = 0;
    float nv =  INFINITY; int nif = 0;
    #pragma unroll
    for (int s = 0; s < 4; ++s) {
        int4 p = partials[a * 16 + q * 4 + s];
        float dv = __int_as_float(p.x);
        bool nr = fabsf(dv - pv) < MARGIN;
        if (dv > pv) { pv = dv; pif = p.y; }
        if (nr) pif |= FLAGBIT;
        float ev = __int_as_float(p.z);
        bool nr2 = fabsf(ev - nv) < MARGIN;
        if (ev < nv) { nv = ev; nif = p.w; }
        if (nr2) nif |= FLAGBIT;
    }
    #pragma unroll
    for (int off = 1; off < 4; off <<= 1) {
        float opv = __shfl_xor(pv, off, 64); int opif = __shfl_xor(pif, off, 64);
        float onv = __shfl_xor(nv, off, 64); int onif = __shfl_xor(nif, off, 64);
        bool pnr = fabsf(opv - pv) < MARGIN;
        bool nnr = fabsf(onv - nv) < MARGIN;
        int opidx = opif & IDXMASK, pidx = pif & IDXMASK;
        if (opv > pv || (opv == pv && opidx < pidx)) { pv = opv; pif = opif; }
        if (pnr) pif |= FLAGBIT;
        int onidx = onif & IDXMASK, nidx = nif & IDXMASK;
        if (onv < nv || (onv == nv && onidx < nidx)) { nv = onv; nif = onif; }
        if (nnr) nif |= FLAGBIT;
    }
    if (q == 0) {
        out[a * 3 + 0] = (float)a;
        out[a * 3 + 1] = (float)(pif & IDXMASK);
        out[a * 3 + 2] = (float)(nif & IDXMASK);
        out[3 * N + a] = pv;
        out[4 * N + a] = nv;
        if ((pif | nif) & FLAGBIT) {
            int k = atomicAdd(counter, 1);
            list[k] = a;
        }
    }
}

// ---------------- cleanup pass 1: exact fp32, one j per thread, u64 atomicMin merge
__global__ __launch_bounds__(256) void cleanup1_kernel(
    const float* __restrict__ e, const int* __restrict__ labels,
    const float* __restrict__ nrm, const int* __restrict__ list,
    const int* __restrict__ counter,
    u64* __restrict__ pos_key, u64* __restrict__ neg_key) {
    __shared__ float enr[128];
    __shared__ u64 redp[4], redn[4];
    const int tid = threadIdx.x;
    const int lane = tid & 63, w = tid >> 6;
    const int cnt = *counter;
    const int j = blockIdx.y * 256 + tid;

    for (int slot = blockIdx.x; slot < cnt; slot += gridDim.x) {
        __syncthreads();                       // protect enr/red reuse
        const int row = list[slot];
        if (tid < 128) enr[tid] = e[(size_t)row * D + tid] / fmaxf(nrm[row], 1e-8f);
        __syncthreads();
        const int lr = labels[row];

        // exact fp32 dot, 4 independent chains
        const float4* ej = (const float4*)(e + (size_t)j * D);
        float s0 = 0.f, s1 = 0.f, s2 = 0.f, s3 = 0.f;
        #pragma unroll
        for (int c = 0; c < 32; c += 4) {
            float4 v0 = ej[c], v1 = ej[c + 1], v2 = ej[c + 2], v3 = ej[c + 3];
            s0 = fmaf(v0.x, enr[4*c   ], fmaf(v0.y, enr[4*c+ 1], fmaf(v0.z, enr[4*c+ 2], fmaf(v0.w, enr[4*c+ 3], s0))));
            s1 = fmaf(v1.x, enr[4*c+ 4], fmaf(v1.y, enr[4*c+ 5], fmaf(v1.z, enr[4*c+ 6], fmaf(v1.w, enr[4*c+ 7], s1))));
            s2 = fmaf(v2.x, enr[4*c+ 8], fmaf(v2.y, enr[4*c+ 9], fmaf(v2.z, enr[4*c+10], fmaf(v2.w, enr[4*c+11], s2))));
            s3 = fmaf(v3.x, enr[4*c+12], fmaf(v3.y, enr[4*c+13], fmaf(v3.z, enr[4*c+14], fmaf(v3.w, enr[4*c+15], s3))));
        }
        float dd = 1.0f - ((s0 + s1) + (s2 + s3)) / fmaxf(nrm[j], 1e-8f);

        u64 pk = ~0ull, nk = ~0ull;
        if (j != row) {
            unsigned int u = ordered_u32(dd);
            if (labels[j] == lr) pk = ((u64)(~u) << 32) | (unsigned int)j;  // max dist, tie min j
            else                 nk = ((u64)( u) << 32) | (unsigned int)j;  // min dist, tie min j
        }
        #pragma unroll
        for (int off = 1; off < 64; off <<= 1) {
            u64 op = __shfl_xor(pk, off, 64); if (op < pk) pk = op;
            u64 on = __shfl_xor(nk, off, 64); if (on < nk) nk = on;
        }
        if (lane == 0) { redp[w] = pk; redn[w] = nk; }
        __syncthreads();
        if (tid == 0) {
            #pragma unroll
            for (int q = 1; q < 4; ++q) {
                if (redp[q] < pk) pk = redp[q];
                if (redn[q] < nk) nk = redn[q];
            }
            if (pk != ~0ull) atomicMin(&pos_key[row], pk);
            if (nk != ~0ull) atomicMin(&neg_key[row], nk);
        }
    }
}

// ---------------- cleanup pass 2: decode keys, overwrite flagged rows ----------
__global__ __launch_bounds__(256) void cleanup2_kernel(
    const u64* __restrict__ pos_key, const u64* __restrict__ neg_key,
    const int* __restrict__ list, const int* __restrict__ counter,
    float* __restrict__ out) {
    int idx = blockIdx.x * 256 + threadIdx.x;
    int cnt = *counter;
    if (idx >= cnt) return;
    int row = list[idx];
    u64 pk = pos_key[row], nk = neg_key[row];
    if (pk != ~0ull) {
        unsigned int u = ~(unsigned int)(pk >> 32);
        out[row * 3 + 1] = (float)(unsigned int)(pk & 0xFFFFFFFFu);
        out[3 * N + row] = ordered_inv(u);
    }
    if (nk != ~0ull) {
        unsigned int u = (unsigned int)(nk >> 32);
        out[row * 3 + 2] = (float)(unsigned int)(nk & 0xFFFFFFFFu);
        out[4 * N + row] = ordered_inv(u);
    }
}

extern "C" void kernel_launch(void* const* d_in, const int* in_sizes, int n_in,
                              void* d_out, int out_size, void* d_ws, size_t ws_size,
                              hipStream_t stream) {
    const float* e      = (const float*)d_in[0];
    const int*   labels = (const int*)d_in[1];
    float* out = (float*)d_out;

    char* wsb = (char*)d_ws;
    __hip_bfloat16* hi = (__hip_bfloat16*)wsb;                          // 2 MB
    __hip_bfloat16* lo = hi + (size_t)N * D;                            // 2 MB
    float* nrm   = (float*)(wsb + 4u * 1024 * 1024);                    // 32 KB
    int4*  parts = (int4*)(wsb + 4u * 1024 * 1024 + 65536);             // 2 MB
    int*   list  = (int*)(wsb + 7u * 1024 * 1024);                      // 32 KB
    int*   cnt   = (int*)(wsb + 7u * 1024 * 1024 + 65536);              // 4 B
    u64*   pkey  = (u64*)(wsb + 7u * 1024 * 1024 + 131072);             // 64 KB
    u64*   nkey  = (u64*)(wsb + 7u * 1024 * 1024 + 196608);             // 64 KB

    prep_kernel<<<N / 4, 256, 0, stream>>>(e, hi, lo, nrm, cnt, pkey, nkey);
    mine_kernel<<<dim3(N / 128, 8), 256, 0, stream>>>(hi, lo, labels, parts);
    combine_kernel<<<N / 64, 256, 0, stream>>>(parts, out, list, cnt);
    cleanup1_kernel<<<dim3(256, 32), 256, 0, stream>>>(e, labels, nrm, list, cnt, pkey, nkey);
    cleanup2_kernel<<<N / 256, 256, 0, stream>>>(pkey, nkey, list, cnt, out);
}